// Round 8
// baseline (121.903 us; speedup 1.0000x reference)
//
#include <hip/hip_runtime.h>

#define INPUT_DIM 128
#define NB 32
#define BS 4
#define CAP 128          // per-node message capacity; degree ~Poisson(32), P(>128)~1e-38
#define NREL 17          // 16 edge relations + self-loop

typedef _Float16 h2 __attribute__((ext_vector_type(2)));
union HU { unsigned int u; h2 h; };

__device__ inline unsigned int pack_f16(float a, float b) {
    HU v; v.h = h2{(_Float16)a, (_Float16)b}; return v.u;
}
__device__ inline h2 as_h2(unsigned int u) { HU v; v.u = u; return v.h; }

// ---------------------------------------------------------------------------
// Workspace layout:
//   counts @0      [n]            int   per-node message count (atomic cursor)
//   msg    @64KB   [n*CAP]        int2  {src | (etype<<16), w-bits}
//   Y      after   [17][n][64]    uint  y = x @ W_r as packed f16 pairs,
//                                       256 B per (r, node) row
// ---------------------------------------------------------------------------

// Fused prep:
//  (a) thread i < n*32: compute Y[r][n][block b] for all 17 r (W staged in LDS)
//  (b) thread i < n_edges: scatter both directions of edge i into dest buckets
__global__ __launch_bounds__(256)
void prep_kernel(const float* __restrict__ x, const float* __restrict__ blocks,
                 const int* __restrict__ src, const int* __restrict__ tgt,
                 const int* __restrict__ etype, const float* __restrict__ ew,
                 int* __restrict__ counts, int2* __restrict__ msg,
                 unsigned int* __restrict__ Y, int n_edges, int n_nodes) {
    __shared__ float Wlds[NREL * NB * 16];   // 34816 B, all 17 relations, f32

    for (int i = threadIdx.x; i < NREL * NB * 4; i += 256)
        ((float4*)Wlds)[i] = ((const float4*)blocks)[i];
    __syncthreads();

    int i = blockIdx.x * blockDim.x + threadIdx.x;

    if (i < n_nodes * NB) {
        int n = i >> 5;
        int b = i & 31;
        const float4 xv = *(const float4*)(x + (size_t)n * INPUT_DIM + b * BS);
        #pragma unroll
        for (int r = 0; r < NREL; ++r) {
            const float4* Wp = (const float4*)&Wlds[(r * NB + b) * 16];
            const float4 c0 = Wp[0], c1 = Wp[1], c2 = Wp[2], c3 = Wp[3];
            float y0 = xv.x * c0.x + xv.y * c1.x + xv.z * c2.x + xv.w * c3.x;
            float y1 = xv.x * c0.y + xv.y * c1.y + xv.z * c2.y + xv.w * c3.y;
            float y2 = xv.x * c0.z + xv.y * c1.z + xv.z * c2.z + xv.w * c3.z;
            float y3 = xv.x * c0.w + xv.y * c1.w + xv.z * c2.w + xv.w * c3.w;
            uint2 o;
            o.x = pack_f16(y0, y1);
            o.y = pack_f16(y2, y3);
            *(uint2*)(Y + (((size_t)(r * n_nodes + n)) << 6) + 2 * b) = o;
        }
    }

    if (i < n_edges) {
        int s = src[i], t = tgt[i];
        int pk_base = etype[i] << 16;
        int wbits = __float_as_int(ew[i]);
        int pf = atomicAdd(&counts[t], 1);
        msg[t * CAP + pf] = make_int2(s | pk_base, wbits);
        int pb = atomicAdd(&counts[s], 1);
        msg[s * CAP + pb] = make_int2(t | pk_base, wbits);
    }
}

// ---------------------------------------------------------------------------
// Gather: ONE node per 64-lane wave. lane = b + 32*slot: lane owns block b,
// slot 0/1 interleave messages (4 per slot in flight per iteration).
// Per message: 8 B msg (broadcast) + 8 B/lane y-row load + 4 cvt + 4 fmac.
// No LDS, no per-message W lookup. Slot halves combined by shfl_xor(32);
// one float4 store per (node, block). Zero f32 atomics.
// ---------------------------------------------------------------------------
__global__ __launch_bounds__(256)
void gather_kernel(const unsigned int* __restrict__ Y,
                   const int* __restrict__ keep,
                   const int* __restrict__ counts,
                   const int2* __restrict__ msg,
                   float* __restrict__ out, int n_nodes) {
    int lane = threadIdx.x & 63;
    int b = lane & 31;
    int slot = lane >> 5;
    int wave_id = (blockIdx.x * blockDim.x + threadIdx.x) >> 6;
    int n_waves = gridDim.x * (blockDim.x >> 6);

    #define DO_MSG(PK, W)                                                       \
        {                                                                       \
            int s_ = (PK) & 0xFFFF;                                             \
            int r_ = (PK) >> 16;                                                \
            const uint2 yp = *(const uint2*)(Y +                                \
                (((size_t)(r_ * n_nodes + s_)) << 6) + 2 * b);                  \
            const h2 lo = as_h2(yp.x), hi = as_h2(yp.y);                        \
            acc.x += (W) * (float)lo.x;                                         \
            acc.y += (W) * (float)lo.y;                                         \
            acc.z += (W) * (float)hi.x;                                         \
            acc.w += (W) * (float)hi.y;                                         \
        }

    for (int n = wave_id; n < n_nodes; n += n_waves) {
        float4 acc = make_float4(0.f, 0.f, 0.f, 0.f);

        // self message: Y[16][n], zeroed for dropped nodes
        if (slot == 0 && keep[n] != 0) {
            const uint2 yp = *(const uint2*)(Y +
                (((size_t)(16 * n_nodes + n)) << 6) + 2 * b);
            const h2 lo = as_h2(yp.x), hi = as_h2(yp.y);
            acc.x = (float)lo.x;
            acc.y = (float)lo.y;
            acc.z = (float)hi.x;
            acc.w = (float)hi.y;
        }

        int cnt = counts[n];
        int base = n * CAP;
        int p = 0;
        // 8 messages per iteration (4 per slot) — loads batched for MLP
        for (; p + 8 <= cnt; p += 8) {
            int2 m0 = msg[base + p + 0 + slot];
            int2 m1 = msg[base + p + 2 + slot];
            int2 m2 = msg[base + p + 4 + slot];
            int2 m3 = msg[base + p + 6 + slot];
            float w0 = __int_as_float(m0.y);
            float w1 = __int_as_float(m1.y);
            float w2 = __int_as_float(m2.y);
            float w3 = __int_as_float(m3.y);
            DO_MSG(m0.x, w0);
            DO_MSG(m1.x, w1);
            DO_MSG(m2.x, w2);
            DO_MSG(m3.x, w3);
        }
        for (; p < cnt; p += 2) {
            if (p + slot < cnt) {
                int2 m = msg[base + p + slot];
                DO_MSG(m.x, __int_as_float(m.y));
            }
        }

        acc.x += __shfl_xor(acc.x, 32, 64);
        acc.y += __shfl_xor(acc.y, 32, 64);
        acc.z += __shfl_xor(acc.z, 32, 64);
        acc.w += __shfl_xor(acc.w, 32, 64);

        if (slot == 0)
            *(float4*)(out + (size_t)n * INPUT_DIM + b * BS) = acc;
    }
    #undef DO_MSG
}

extern "C" void kernel_launch(void* const* d_in, const int* in_sizes, int n_in,
                              void* d_out, int out_size, void* d_ws, size_t ws_size,
                              hipStream_t stream) {
    const float* x       = (const float*)d_in[0];
    const int* km        = (const int*)d_in[1];
    const int* source    = (const int*)d_in[2];
    const int* target    = (const int*)d_in[3];
    const int* edge_type = (const int*)d_in[4];
    const float* edge_w  = (const float*)d_in[5];
    const float* blocks  = (const float*)d_in[6];
    float* out           = (float*)d_out;

    int n_nodes = in_sizes[0] / INPUT_DIM;   // 10000
    int n_edges = in_sizes[2];               // 160000

    // workspace: counts @0 (40KB), msg @64KB (10.24MB), Y after (43.52MB)
    size_t msg_bytes = (size_t)n_nodes * CAP * sizeof(int2);
    int* counts      = (int*)d_ws;
    int2* msg        = (int2*)((char*)d_ws + 65536);
    unsigned int* Y  = (unsigned int*)((char*)d_ws + 65536 + msg_bytes);

    hipMemsetAsync(counts, 0, n_nodes * sizeof(int), stream);

    int prep_threads = n_nodes * NB;         // 320000 (covers n_edges too)
    prep_kernel<<<(prep_threads + 255) / 256, 256, 0, stream>>>(
        x, blocks, source, target, edge_type, edge_w, counts, msg, Y,
        n_edges, n_nodes);

    int gather_threads = n_nodes * 64;       // one 64-lane wave per node
    gather_kernel<<<(gather_threads + 255) / 256, 256, 0, stream>>>(
        Y, km, counts, msg, out, n_nodes);
}

// Round 10
// 110.249 us; speedup vs baseline: 1.1057x; 1.1057x over previous
//
#include <hip/hip_runtime.h>

#define INPUT_DIM 128
#define NB 32
#define BS 4
#define CAP 128          // per-node message capacity; degree ~Poisson(32), P(>128)~1e-38
#define WSTRIDE_U 12     // uints per 4x4 f16 block in LDS: 8 + 4 pad (16B-aligned)
#define GBLOCKS 1280     // gather grid: 4 waves/block -> 5120 waves, ~2 nodes/wave

typedef _Float16 h2 __attribute__((ext_vector_type(2)));
union HU { unsigned int u; h2 h; };

__device__ inline unsigned int pack_f16(float a, float b) {
    HU v; v.h = h2{(_Float16)a, (_Float16)b}; return v.u;
}
__device__ inline h2 as_h2(unsigned int u) { HU v; v.u = u; return v.h; }

__device__ inline float dot2(h2 a, h2 b, float c) {
    return __builtin_amdgcn_fdot2(a, b, c, false);
}

// ---------------------------------------------------------------------------
// Workspace layout:
//   counts @0      [n]       int   per-node message count (atomic cursor)
//   xh     @64KB   [n*64]    uint  x as packed f16 pairs (2.56 MB, L2-resident)
//   msg    after   [n*CAP]   int2  {src | (etype<<16), w-bits}
// ---------------------------------------------------------------------------

// Fused prep: (a) convert 8 f32 x elements -> 4 packed-f16 uints,
//             (b) scatter both directions of edge i into dest buckets.
__global__ void prep_kernel(const float* __restrict__ x, unsigned int* __restrict__ xh,
                            const int* __restrict__ src, const int* __restrict__ tgt,
                            const int* __restrict__ etype, const float* __restrict__ ew,
                            int* __restrict__ counts, int2* __restrict__ msg,
                            int n_edges, int nx8) {
    int i = blockIdx.x * blockDim.x + threadIdx.x;
    if (i < nx8) {
        const float4 a = *(const float4*)(x + (size_t)i * 8);
        const float4 b = *(const float4*)(x + (size_t)i * 8 + 4);
        uint4 o;
        o.x = pack_f16(a.x, a.y);
        o.y = pack_f16(a.z, a.w);
        o.z = pack_f16(b.x, b.y);
        o.w = pack_f16(b.z, b.w);
        *(uint4*)(xh + (size_t)i * 4) = o;
    }
    if (i < n_edges) {
        int s = src[i], t = tgt[i];
        int pk_base = etype[i] << 16;
        int wbits = __float_as_int(ew[i]);
        int pf = atomicAdd(&counts[t], 1);
        msg[t * CAP + pf] = make_int2(s | pk_base, wbits);
        int pb = atomicAdd(&counts[s], 1);
        msg[s * CAP + pb] = make_int2(t | pk_base, wbits);
    }
}

// ---------------------------------------------------------------------------
// Gather: ONE node per 64-lane wave. lane = b + 32*slot: lane owns block b,
// slot 0/1 process alternating messages. KEY CHANGE vs R6: message loads use
// wave-UNIFORM addresses (msg[base+p+i], no +slot) so the compiler can emit
// scalar (SMEM) loads — one issue per wave, off the VMEM critical path; slot
// picks its message via cndmask on the SGPR-held values. cnt/base forced
// scalar via readfirstlane. W (rel 0..15) in LDS as packed f16 col-pairs.
// Slot halves combined by shfl_xor(32); one float4 store per (node, block).
// ---------------------------------------------------------------------------
__global__ __launch_bounds__(256, 4)
void gather_kernel(const float* __restrict__ x,
                   const unsigned int* __restrict__ xh,
                   const int* __restrict__ keep,
                   const float* __restrict__ blocks,
                   const int* __restrict__ counts,
                   const int2* __restrict__ msg,
                   float* __restrict__ out, int n_nodes) {
    __shared__ unsigned int Wlds[16 * NB * WSTRIDE_U];   // 24576 B

    // stage + convert relations 0..15 (512 blocks of 4x4 f32)
    for (int bi = threadIdx.x; bi < 16 * NB; bi += 256) {
        const float4 r0 = ((const float4*)blocks)[bi * 4 + 0];
        const float4 r1 = ((const float4*)blocks)[bi * 4 + 1];
        const float4 r2 = ((const float4*)blocks)[bi * 4 + 2];
        const float4 r3 = ((const float4*)blocks)[bi * 4 + 3];
        // lo_j = (W[0][j], W[1][j]), hi_j = (W[2][j], W[3][j])
        uint4 q0, q1;
        q0.x = pack_f16(r0.x, r1.x); q0.y = pack_f16(r2.x, r3.x);  // j=0
        q0.z = pack_f16(r0.y, r1.y); q0.w = pack_f16(r2.y, r3.y);  // j=1
        q1.x = pack_f16(r0.z, r1.z); q1.y = pack_f16(r2.z, r3.z);  // j=2
        q1.z = pack_f16(r0.w, r1.w); q1.w = pack_f16(r2.w, r3.w);  // j=3
        *(uint4*)&Wlds[bi * WSTRIDE_U + 0] = q0;
        *(uint4*)&Wlds[bi * WSTRIDE_U + 4] = q1;
    }
    __syncthreads();

    int lane = threadIdx.x & 63;
    int b = lane & 31;
    int slot = lane >> 5;
    int wave_id = (blockIdx.x * blockDim.x + threadIdx.x) >> 6;
    int n_waves = gridDim.x * (blockDim.x >> 6);

    #define DO_MSG(PK, W)                                                     \
        {                                                                     \
            int s_ = (PK) & 0xFFFF;                                           \
            int r_ = (PK) >> 16;                                              \
            const unsigned int* Wp_ = &Wlds[(r_ * NB + b) * WSTRIDE_U];       \
            const uint4 q0 = *(const uint4*)(Wp_ + 0);                        \
            const uint4 q1 = *(const uint4*)(Wp_ + 4);                        \
            const uint2 xp = *(const uint2*)(xh + s_ * 64 + 2 * b);           \
            const h2 xl = as_h2(xp.x), xhh = as_h2(xp.y);                     \
            float m0 = dot2(xl, as_h2(q0.x), dot2(xhh, as_h2(q0.y), 0.f));    \
            float m1 = dot2(xl, as_h2(q0.z), dot2(xhh, as_h2(q0.w), 0.f));    \
            float m2 = dot2(xl, as_h2(q1.x), dot2(xhh, as_h2(q1.y), 0.f));    \
            float m3 = dot2(xl, as_h2(q1.z), dot2(xhh, as_h2(q1.w), 0.f));    \
            acc.x += (W) * m0;                                                \
            acc.y += (W) * m1;                                                \
            acc.z += (W) * m2;                                                \
            acc.w += (W) * m3;                                                \
        }

    // slot-selects one of two scalar-held messages, then does the math
    #define DO_PAIR(MA, MB)                                                   \
        {                                                                     \
            int pk_ = slot ? (MB).x : (MA).x;                                 \
            float w_ = __int_as_float(slot ? (MB).y : (MA).y);                \
            DO_MSG(pk_, w_);                                                  \
        }

    for (int n = wave_id; n < n_nodes; n += n_waves) {
        float4 acc = make_float4(0.f, 0.f, 0.f, 0.f);

        // self message (relation 16): full f32 path, once per node
        if (slot == 0 && keep[n] != 0) {
            const float4 xv = *(const float4*)(x + (size_t)n * INPUT_DIM + b * BS);
            const float* Wp = blocks + (((size_t)16 * NB + b) << 4);
            const float4 c0 = *(const float4*)(Wp + 0);
            const float4 c1 = *(const float4*)(Wp + 4);
            const float4 c2 = *(const float4*)(Wp + 8);
            const float4 c3 = *(const float4*)(Wp + 12);
            acc.x = xv.x * c0.x + xv.y * c1.x + xv.z * c2.x + xv.w * c3.x;
            acc.y = xv.x * c0.y + xv.y * c1.y + xv.z * c2.y + xv.w * c3.y;
            acc.z = xv.x * c0.z + xv.y * c1.z + xv.z * c2.z + xv.w * c3.z;
            acc.w = xv.x * c0.w + xv.y * c1.w + xv.z * c2.w + xv.w * c3.w;
        }

        int cnt = __builtin_amdgcn_readfirstlane(counts[n]);
        const int2* mb = msg + __builtin_amdgcn_readfirstlane(n * CAP);

        int p = 0;
        // 8 messages per iteration, loaded at wave-uniform addresses
        for (; p + 8 <= cnt; p += 8) {
            int2 a0 = mb[p + 0];
            int2 a1 = mb[p + 1];
            int2 a2 = mb[p + 2];
            int2 a3 = mb[p + 3];
            int2 a4 = mb[p + 4];
            int2 a5 = mb[p + 5];
            int2 a6 = mb[p + 6];
            int2 a7 = mb[p + 7];
            DO_PAIR(a0, a1);
            DO_PAIR(a2, a3);
            DO_PAIR(a4, a5);
            DO_PAIR(a6, a7);
        }
        for (; p < cnt; p += 2) {
            int2 a0 = mb[p];
            int2 a1 = (p + 1 < cnt) ? mb[p + 1] : make_int2(0, 0);  // w=0 no-op
            DO_PAIR(a0, a1);
        }

        acc.x += __shfl_xor(acc.x, 32, 64);
        acc.y += __shfl_xor(acc.y, 32, 64);
        acc.z += __shfl_xor(acc.z, 32, 64);
        acc.w += __shfl_xor(acc.w, 32, 64);

        if (slot == 0)
            *(float4*)(out + (size_t)n * INPUT_DIM + b * BS) = acc;
    }
    #undef DO_PAIR
    #undef DO_MSG
}

extern "C" void kernel_launch(void* const* d_in, const int* in_sizes, int n_in,
                              void* d_out, int out_size, void* d_ws, size_t ws_size,
                              hipStream_t stream) {
    const float* x       = (const float*)d_in[0];
    const int* km        = (const int*)d_in[1];
    const int* source    = (const int*)d_in[2];
    const int* target    = (const int*)d_in[3];
    const int* edge_type = (const int*)d_in[4];
    const float* edge_w  = (const float*)d_in[5];
    const float* blocks  = (const float*)d_in[6];
    float* out           = (float*)d_out;

    int n_nodes = in_sizes[0] / INPUT_DIM;   // 10000
    int n_edges = in_sizes[2];               // 160000
    int nx8     = n_nodes * INPUT_DIM / 8;   // 160000 x-convert units

    // workspace: counts @0 (40KB), xh @64KB (2.56MB), msg after (10.24MB)
    int* counts      = (int*)d_ws;
    unsigned int* xh = (unsigned int*)((char*)d_ws + 65536);
    int2* msg        = (int2*)((char*)d_ws + 65536 + (size_t)n_nodes * INPUT_DIM * 2);

    hipMemsetAsync(counts, 0, n_nodes * sizeof(int), stream);
    int prep_threads = (n_edges > nx8) ? n_edges : nx8;
    prep_kernel<<<(prep_threads + 255) / 256, 256, 0, stream>>>(
        x, xh, source, target, edge_type, edge_w, counts, msg, n_edges, nx8);
    gather_kernel<<<GBLOCKS, 256, 0, stream>>>(
        x, xh, km, blocks, counts, msg, out, n_nodes);
}